// Round 1
// baseline (2214.074 us; speedup 1.0000x reference)
//
#include <hip/hip_runtime.h>

static constexpr int N_NODES = 50000;
static constexpr int N_EDGES = 1600000;
static constexpr int CIN = 32;
static constexpr int HID = 64;

// ws layout (floats):
//   cnt  : [0, N)
//   agg0 : [N, N + N*32)
//   agg1 : [N + N*32, N + N*32 + N*64)
//   h    : [N + N*96, N + N*96 + N*64)
// cnt+agg0+agg1 are contiguous -> one memsetAsync of N*97 floats.

__global__ void edge_agg0_kernel(const int* __restrict__ ei,
                                 const float* __restrict__ x,
                                 float* __restrict__ agg,
                                 float* __restrict__ cnt) {
    const int total = N_EDGES * 8;               // 8 float4 chunks per edge
    for (int i = blockIdx.x * blockDim.x + threadIdx.x; i < total;
         i += gridDim.x * blockDim.x) {
        const int e = i >> 3;
        const int c = i & 7;
        const int s = ei[e];
        const int d = ei[N_EDGES + e];
        const float4 v = *reinterpret_cast<const float4*>(x + (size_t)s * CIN + c * 4);
        float* a = agg + (size_t)d * CIN + c * 4;
        atomicAdd(a + 0, v.x);
        atomicAdd(a + 1, v.y);
        atomicAdd(a + 2, v.z);
        atomicAdd(a + 3, v.w);
        if (c == 0) atomicAdd(cnt + d, 1.0f);
    }
}

__global__ void edge_agg1_kernel(const int* __restrict__ ei,
                                 const float* __restrict__ h,
                                 float* __restrict__ agg) {
    const int total = N_EDGES * 16;              // 16 float4 chunks per edge
    for (int i = blockIdx.x * blockDim.x + threadIdx.x; i < total;
         i += gridDim.x * blockDim.x) {
        const int e = i >> 4;
        const int c = i & 15;
        const int s = ei[e];
        const int d = ei[N_EDGES + e];
        const float4 v = *reinterpret_cast<const float4*>(h + (size_t)s * HID + c * 4);
        float* a = agg + (size_t)d * HID + c * 4;
        atomicAdd(a + 0, v.x);
        atomicAdd(a + 1, v.y);
        atomicAdd(a + 2, v.z);
        atomicAdd(a + 3, v.w);
    }
}

// one wave (64 lanes) per node; lane = output channel
__global__ void node0_kernel(const float* __restrict__ x,
                             const float* __restrict__ agg,
                             const float* __restrict__ cnt,
                             const float* __restrict__ Wl,
                             const float* __restrict__ Wr,
                             const float* __restrict__ b,
                             float* __restrict__ h) {
    const int node = blockIdx.x * 4 + (threadIdx.x >> 6);
    const int lane = threadIdx.x & 63;
    if (node >= N_NODES) return;
    const float inv = 1.0f / fmaxf(cnt[node], 1.0f);
    const float* ax = agg + (size_t)node * CIN;
    const float* xx = x + (size_t)node * CIN;
    float acc = b[lane];
#pragma unroll
    for (int k = 0; k < CIN; ++k) {
        acc = fmaf(ax[k] * inv, Wl[k * HID + lane], acc);
        acc = fmaf(xx[k], Wr[k * HID + lane], acc);
    }
    float ss = acc * acc;
#pragma unroll
    for (int m = 32; m > 0; m >>= 1) ss += __shfl_xor(ss, m);
    const float o = acc / fmaxf(sqrtf(ss), 1e-12f);
    h[(size_t)node * HID + lane] = fmaxf(o, 0.0f);   // relu
}

// one wave per node: sage layer 1 (normalize, no relu) + classifier fused
__global__ void node1_kernel(const float* __restrict__ h,
                             const float* __restrict__ agg,
                             const float* __restrict__ cnt,
                             const float* __restrict__ Wl,
                             const float* __restrict__ Wr,
                             const float* __restrict__ b,
                             const float* __restrict__ Wc1,
                             const float* __restrict__ bc1,
                             const float* __restrict__ Wc2,
                             const float* __restrict__ bc2,
                             float* __restrict__ out) {
    const int node = blockIdx.x * 4 + (threadIdx.x >> 6);
    const int lane = threadIdx.x & 63;
    if (node >= N_NODES) return;
    const float inv = 1.0f / fmaxf(cnt[node], 1.0f);
    const float* ah = agg + (size_t)node * HID;
    const float* hh = h + (size_t)node * HID;
    float acc = b[lane];
#pragma unroll
    for (int k = 0; k < HID; ++k) {
        acc = fmaf(ah[k] * inv, Wl[k * HID + lane], acc);
        acc = fmaf(hh[k], Wr[k * HID + lane], acc);
    }
    float ss = acc * acc;
#pragma unroll
    for (int m = 32; m > 0; m >>= 1) ss += __shfl_xor(ss, m);
    const float v = acc / fmaxf(sqrtf(ss), 1e-12f);   // normalized h2[lane]

    // classifier: lanes 0..31 each own one hidden unit j = lane
    const int j = lane & 31;
    float cacc = bc1[j];
#pragma unroll
    for (int o = 0; o < HID; ++o) {
        const float vo = __shfl(v, o);                // broadcast h2[o]
        cacc = fmaf(vo, Wc1[o * 32 + j], cacc);
    }
    float partial = (lane < 32) ? fmaxf(cacc, 0.0f) * Wc2[j] : 0.0f;
#pragma unroll
    for (int m = 32; m > 0; m >>= 1) partial += __shfl_xor(partial, m);
    if (lane == 0) out[node] = partial + bc2[0];
}

extern "C" void kernel_launch(void* const* d_in, const int* in_sizes, int n_in,
                              void* d_out, int out_size, void* d_ws, size_t ws_size,
                              hipStream_t stream) {
    const float* x   = (const float*)d_in[0];
    const int*   ei  = (const int*)d_in[1];
    const float* Wl0 = (const float*)d_in[2];
    const float* b0  = (const float*)d_in[3];
    const float* Wr0 = (const float*)d_in[4];
    const float* Wl1 = (const float*)d_in[5];
    const float* b1  = (const float*)d_in[6];
    const float* Wr1 = (const float*)d_in[7];
    const float* Wc1 = (const float*)d_in[8];
    const float* bc1 = (const float*)d_in[9];
    const float* Wc2 = (const float*)d_in[10];
    const float* bc2 = (const float*)d_in[11];
    float* out = (float*)d_out;

    float* ws   = (float*)d_ws;
    float* cnt  = ws;                                  // N
    float* agg0 = ws + N_NODES;                        // N*32
    float* agg1 = ws + N_NODES + (size_t)N_NODES * 32; // N*64
    float* h    = agg1 + (size_t)N_NODES * 64;         // N*64

    // zero cnt + agg0 + agg1 in one shot (contiguous)
    hipMemsetAsync(ws, 0, (size_t)N_NODES * 97 * sizeof(float), stream);

    const int threads = 256;
    const int egrid = 2048;
    edge_agg0_kernel<<<egrid, threads, 0, stream>>>(ei, x, agg0, cnt);

    const int ngrid = (N_NODES + 3) / 4;               // 4 nodes (waves) per block
    node0_kernel<<<ngrid, threads, 0, stream>>>(x, agg0, cnt, Wl0, Wr0, b0, h);

    edge_agg1_kernel<<<egrid, threads, 0, stream>>>(ei, h, agg1);

    node1_kernel<<<ngrid, threads, 0, stream>>>(h, agg1, cnt, Wl1, Wr1, b1,
                                                Wc1, bc1, Wc2, bc2, out);
}

// Round 2
// 641.315 us; speedup vs baseline: 3.4524x; 3.4524x over previous
//
#include <hip/hip_runtime.h>

static constexpr int N_NODES = 50000;
static constexpr int N_EDGES = 1600000;
static constexpr int CIN = 32;
static constexpr int HID = 64;
static constexpr int SCAN_T = 1024;

// ---------------- CSR build ----------------

__global__ void hist_kernel(const int* __restrict__ ei, int* __restrict__ deg) {
    int i = blockIdx.x * blockDim.x + threadIdx.x;
    if (i < N_EDGES) atomicAdd(&deg[ei[N_EDGES + i]], 1);
}

// single block: exclusive scan of deg[N] -> off[N+1], copy to cursor[N]
__global__ void scan_kernel(const int* __restrict__ deg,
                            int* __restrict__ off,
                            int* __restrict__ cursor) {
    __shared__ int sdata[SCAN_T];
    const int t = threadIdx.x;
    const int chunk = (N_NODES + SCAN_T - 1) / SCAN_T;
    const int lo = t * chunk;
    const int hi = min(lo + chunk, N_NODES);
    int local = 0;
    for (int i = lo; i < hi; ++i) local += deg[i];
    sdata[t] = local;
    __syncthreads();
    // Hillis-Steele inclusive scan
    for (int s = 1; s < SCAN_T; s <<= 1) {
        int v = (t >= s) ? sdata[t - s] : 0;
        __syncthreads();
        sdata[t] += v;
        __syncthreads();
    }
    int run = sdata[t] - local;   // exclusive base for this chunk
    for (int i = lo; i < hi; ++i) {
        off[i] = run;
        cursor[i] = run;
        run += deg[i];
    }
    if (t == 0) off[N_NODES] = N_EDGES;
}

__global__ void scatter_kernel(const int* __restrict__ ei,
                               int* __restrict__ cursor,
                               int* __restrict__ sorted_src) {
    int i = blockIdx.x * blockDim.x + threadIdx.x;
    if (i < N_EDGES) {
        const int d = ei[N_EDGES + i];
        const int pos = atomicAdd(&cursor[d], 1);
        sorted_src[pos] = ei[i];
    }
}

// ---------------- layer 0: mean-agg (CIN=32) + linear + L2norm + relu ----------------
// one wave per node; lane<32 & lane>=32 process alternating edges; c = lane&31
__global__ void layer0_kernel(const float* __restrict__ x,
                              const int* __restrict__ off,
                              const int* __restrict__ src,
                              const float* __restrict__ Wl,
                              const float* __restrict__ Wr,
                              const float* __restrict__ b,
                              float* __restrict__ h) {
    const int node = blockIdx.x * 4 + (threadIdx.x >> 6);
    const int lane = threadIdx.x & 63;
    if (node >= N_NODES) return;
    const int e0 = off[node], e1 = off[node + 1];
    const int half = lane >> 5;
    const int c = lane & 31;
    float acc = 0.0f;
    for (int e = e0 + half; e < e1; e += 2) {
        const int s = src[e];
        acc += x[(size_t)s * CIN + c];
    }
    acc += __shfl_xor(acc, 32);               // combine the two halves
    const float deg = (float)(e1 - e0);
    const float mean = acc / fmaxf(deg, 1.0f); // lane k (and k+32) holds mean[k&31]

    const float* xx = x + (size_t)node * CIN;
    float o = b[lane];
#pragma unroll
    for (int k = 0; k < CIN; ++k) {
        const float mk = __shfl(mean, k);
        o = fmaf(mk, Wl[k * HID + lane], o);
        o = fmaf(xx[k], Wr[k * HID + lane], o);
    }
    float ss = o * o;
#pragma unroll
    for (int m = 32; m > 0; m >>= 1) ss += __shfl_xor(ss, m);
    const float v = o / fmaxf(sqrtf(ss), 1e-12f);
    h[(size_t)node * HID + lane] = fmaxf(v, 0.0f);   // relu
}

// ---------------- layer 1: mean-agg (HID=64) + linear + L2norm + classifier ----------------
__global__ void layer1_kernel(const float* __restrict__ h,
                              const int* __restrict__ off,
                              const int* __restrict__ src,
                              const float* __restrict__ Wl,
                              const float* __restrict__ Wr,
                              const float* __restrict__ b,
                              const float* __restrict__ Wc1,
                              const float* __restrict__ bc1,
                              const float* __restrict__ Wc2,
                              const float* __restrict__ bc2,
                              float* __restrict__ out) {
    const int node = blockIdx.x * 4 + (threadIdx.x >> 6);
    const int lane = threadIdx.x & 63;
    if (node >= N_NODES) return;
    const int e0 = off[node], e1 = off[node + 1];
    float acc = 0.0f;
    for (int e = e0; e < e1; ++e) {
        const int s = src[e];
        acc += h[(size_t)s * HID + lane];      // 256B coalesced per edge
    }
    const float deg = (float)(e1 - e0);
    const float mean = acc / fmaxf(deg, 1.0f); // lane k holds mean[k]

    const float* hh = h + (size_t)node * HID;
    float o = b[lane];
#pragma unroll
    for (int k = 0; k < HID; ++k) {
        const float mk = __shfl(mean, k);
        o = fmaf(mk, Wl[k * HID + lane], o);
        o = fmaf(hh[k], Wr[k * HID + lane], o);
    }
    float ss = o * o;
#pragma unroll
    for (int m = 32; m > 0; m >>= 1) ss += __shfl_xor(ss, m);
    const float v = o / fmaxf(sqrtf(ss), 1e-12f);  // normalized h2[lane]

    // classifier: lanes pair up on 32 hidden units
    const int j = lane & 31;
    float cacc = bc1[j];
#pragma unroll
    for (int oo = 0; oo < HID; ++oo) {
        const float vo = __shfl(v, oo);
        cacc = fmaf(vo, Wc1[oo * 32 + j], cacc);
    }
    float partial = (lane < 32) ? fmaxf(cacc, 0.0f) * Wc2[j] : 0.0f;
#pragma unroll
    for (int m = 32; m > 0; m >>= 1) partial += __shfl_xor(partial, m);
    if (lane == 0) out[node] = partial + bc2[0];
}

extern "C" void kernel_launch(void* const* d_in, const int* in_sizes, int n_in,
                              void* d_out, int out_size, void* d_ws, size_t ws_size,
                              hipStream_t stream) {
    const float* x   = (const float*)d_in[0];
    const int*   ei  = (const int*)d_in[1];
    const float* Wl0 = (const float*)d_in[2];
    const float* b0  = (const float*)d_in[3];
    const float* Wr0 = (const float*)d_in[4];
    const float* Wl1 = (const float*)d_in[5];
    const float* b1  = (const float*)d_in[6];
    const float* Wr1 = (const float*)d_in[7];
    const float* Wc1 = (const float*)d_in[8];
    const float* bc1 = (const float*)d_in[9];
    const float* Wc2 = (const float*)d_in[10];
    const float* bc2 = (const float*)d_in[11];
    float* out = (float*)d_out;

    // ws layout (4B elems)
    int*   deg        = (int*)d_ws;                        // N
    int*   off        = deg + N_NODES;                     // N+1
    int*   cursor     = off + N_NODES + 1;                 // N
    int*   sorted_src = cursor + N_NODES;                  // E
    size_t used       = 3 * (size_t)N_NODES + 1 + N_EDGES;
    used              = (used + 15) & ~(size_t)15;         // align
    float* h          = (float*)d_ws + used;               // N*64

    hipMemsetAsync(deg, 0, N_NODES * sizeof(int), stream);

    const int T = 256;
    hist_kernel<<<(N_EDGES + T - 1) / T, T, 0, stream>>>(ei, deg);
    scan_kernel<<<1, SCAN_T, 0, stream>>>(deg, off, cursor);
    scatter_kernel<<<(N_EDGES + T - 1) / T, T, 0, stream>>>(ei, cursor, sorted_src);

    const int ngrid = (N_NODES + 3) / 4;   // 4 waves (nodes) per 256-thread block
    layer0_kernel<<<ngrid, T, 0, stream>>>(x, off, sorted_src, Wl0, Wr0, b0, h);
    layer1_kernel<<<ngrid, T, 0, stream>>>(h, off, sorted_src, Wl1, Wr1, b1,
                                           Wc1, bc1, Wc2, bc2, out);
}

// Round 3
// 468.781 us; speedup vs baseline: 4.7230x; 1.3680x over previous
//
#include <hip/hip_runtime.h>

static constexpr int N_NODES = 50000;
static constexpr int N_EDGES = 1600000;
static constexpr int CIN = 32;
static constexpr int HID = 64;
static constexpr int SCAN_T = 1024;

// ---------------- CSR build ----------------

__global__ void hist_kernel(const int* __restrict__ ei, int* __restrict__ deg) {
    int i = blockIdx.x * blockDim.x + threadIdx.x;
    if (i < N_EDGES) atomicAdd(&deg[ei[N_EDGES + i]], 1);
}

// single block: exclusive scan of deg[N] -> off[N+1], copy to cursor[N]
__global__ void scan_kernel(const int* __restrict__ deg,
                            int* __restrict__ off,
                            int* __restrict__ cursor) {
    __shared__ int sdata[SCAN_T];
    const int t = threadIdx.x;
    const int chunk = (N_NODES + SCAN_T - 1) / SCAN_T;
    const int lo = t * chunk;
    const int hi = min(lo + chunk, N_NODES);
    int local = 0;
    for (int i = lo; i < hi; ++i) local += deg[i];
    sdata[t] = local;
    __syncthreads();
    for (int s = 1; s < SCAN_T; s <<= 1) {
        int v = (t >= s) ? sdata[t - s] : 0;
        __syncthreads();
        sdata[t] += v;
        __syncthreads();
    }
    int run = sdata[t] - local;
    for (int i = lo; i < hi; ++i) {
        off[i] = run;
        cursor[i] = run;
        run += deg[i];
    }
    if (t == 0) off[N_NODES] = N_EDGES;
}

__global__ void scatter_kernel(const int* __restrict__ ei,
                               int* __restrict__ cursor,
                               int* __restrict__ sorted_src) {
    int i = blockIdx.x * blockDim.x + threadIdx.x;
    if (i < N_EDGES) {
        const int d = ei[N_EDGES + i];
        const int pos = atomicAdd(&cursor[d], 1);
        sorted_src[pos] = ei[i];
    }
}

// ---------------- layer 0 ----------------
// one wave per node. Gather: 8 lanes per edge-row (float4 each), 8 edges per
// wave-instruction. Lane l: edge e0 + (l>>3) (step 8), channels 4*(l&7)..+3.
__global__ void layer0_kernel(const float* __restrict__ x,
                              const int* __restrict__ off,
                              const int* __restrict__ src,
                              const float* __restrict__ Wl,
                              const float* __restrict__ Wr,
                              const float* __restrict__ b,
                              float* __restrict__ h) {
    const int node = blockIdx.x * 4 + (threadIdx.x >> 6);
    const int lane = threadIdx.x & 63;
    if (node >= N_NODES) return;
    const int e0 = off[node], e1 = off[node + 1];
    const int grp = lane >> 3;       // 0..7  edge slot
    const int cg  = lane & 7;        // channel group (4 ch)

    float4 a0 = make_float4(0.f, 0.f, 0.f, 0.f);
    float4 a1 = make_float4(0.f, 0.f, 0.f, 0.f);
    for (int e = e0 + grp; e < e1; e += 16) {
        {
            const int s = src[e];
            const float4 v = *reinterpret_cast<const float4*>(x + (size_t)s * CIN + cg * 4);
            a0.x += v.x; a0.y += v.y; a0.z += v.z; a0.w += v.w;
        }
        const int e2 = e + 8;
        if (e2 < e1) {
            const int s = src[e2];
            const float4 v = *reinterpret_cast<const float4*>(x + (size_t)s * CIN + cg * 4);
            a1.x += v.x; a1.y += v.y; a1.z += v.z; a1.w += v.w;
        }
    }
    float m4[4] = {a0.x + a1.x, a0.y + a1.y, a0.z + a1.z, a0.w + a1.w};
#pragma unroll
    for (int j = 0; j < 4; ++j) {
        m4[j] += __shfl_xor(m4[j], 8);
        m4[j] += __shfl_xor(m4[j], 16);
        m4[j] += __shfl_xor(m4[j], 32);
    }
    const float inv = 1.0f / fmaxf((float)(e1 - e0), 1.0f);
#pragma unroll
    for (int j = 0; j < 4; ++j) m4[j] *= inv;   // mean for ch 4*cg+j (all grp share)

    // self row as float4 per lane (redundant across grp, L1 broadcast)
    const float4 xs = *reinterpret_cast<const float4*>(x + (size_t)node * CIN + cg * 4);
    float x4[4] = {xs.x, xs.y, xs.z, xs.w};

    float o = b[lane];
#pragma unroll
    for (int k = 0; k < CIN; ++k) {
        const float mk = __shfl(m4[k & 3], k >> 2);   // holder lane = k>>2
        const float xk = __shfl(x4[k & 3], k >> 2);
        o = fmaf(mk, Wl[k * HID + lane], o);
        o = fmaf(xk, Wr[k * HID + lane], o);
    }
    float ss = o * o;
#pragma unroll
    for (int m = 32; m > 0; m >>= 1) ss += __shfl_xor(ss, m);
    const float v = o / fmaxf(sqrtf(ss), 1e-12f);
    h[(size_t)node * HID + lane] = fmaxf(v, 0.0f);
}

// ---------------- layer 1 + classifier ----------------
// Gather: 16 lanes per edge-row (float4), 4 edges per wave-instruction.
__global__ void layer1_kernel(const float* __restrict__ h,
                              const int* __restrict__ off,
                              const int* __restrict__ src,
                              const float* __restrict__ Wl,
                              const float* __restrict__ Wr,
                              const float* __restrict__ b,
                              const float* __restrict__ Wc1,
                              const float* __restrict__ bc1,
                              const float* __restrict__ Wc2,
                              const float* __restrict__ bc2,
                              float* __restrict__ out) {
    const int node = blockIdx.x * 4 + (threadIdx.x >> 6);
    const int lane = threadIdx.x & 63;
    if (node >= N_NODES) return;
    const int e0 = off[node], e1 = off[node + 1];
    const int grp = lane >> 4;       // 0..3  edge slot
    const int cg  = lane & 15;       // channel group (4 ch)

    float4 a0 = make_float4(0.f, 0.f, 0.f, 0.f);
    float4 a1 = make_float4(0.f, 0.f, 0.f, 0.f);
    for (int e = e0 + grp; e < e1; e += 8) {
        {
            const int s = src[e];
            const float4 v = *reinterpret_cast<const float4*>(h + (size_t)s * HID + cg * 4);
            a0.x += v.x; a0.y += v.y; a0.z += v.z; a0.w += v.w;
        }
        const int e2 = e + 4;
        if (e2 < e1) {
            const int s = src[e2];
            const float4 v = *reinterpret_cast<const float4*>(h + (size_t)s * HID + cg * 4);
            a1.x += v.x; a1.y += v.y; a1.z += v.z; a1.w += v.w;
        }
    }
    float m4[4] = {a0.x + a1.x, a0.y + a1.y, a0.z + a1.z, a0.w + a1.w};
#pragma unroll
    for (int j = 0; j < 4; ++j) {
        m4[j] += __shfl_xor(m4[j], 16);
        m4[j] += __shfl_xor(m4[j], 32);
    }
    const float inv = 1.0f / fmaxf((float)(e1 - e0), 1.0f);
#pragma unroll
    for (int j = 0; j < 4; ++j) m4[j] *= inv;   // mean for ch 4*cg+j

    const float4 hs = *reinterpret_cast<const float4*>(h + (size_t)node * HID + cg * 4);
    float h4[4] = {hs.x, hs.y, hs.z, hs.w};

    float o = b[lane];
#pragma unroll
    for (int k = 0; k < HID; ++k) {
        const float mk = __shfl(m4[k & 3], k >> 2);   // holder lane = k>>2 (cg match)
        const float hk = __shfl(h4[k & 3], k >> 2);
        o = fmaf(mk, Wl[k * HID + lane], o);
        o = fmaf(hk, Wr[k * HID + lane], o);
    }
    float ss = o * o;
#pragma unroll
    for (int m = 32; m > 0; m >>= 1) ss += __shfl_xor(ss, m);
    const float v = o / fmaxf(sqrtf(ss), 1e-12f);   // normalized h2[lane]

    const int j = lane & 31;
    float cacc = bc1[j];
#pragma unroll
    for (int oo = 0; oo < HID; ++oo) {
        const float vo = __shfl(v, oo);
        cacc = fmaf(vo, Wc1[oo * 32 + j], cacc);
    }
    float partial = (lane < 32) ? fmaxf(cacc, 0.0f) * Wc2[j] : 0.0f;
#pragma unroll
    for (int m = 32; m > 0; m >>= 1) partial += __shfl_xor(partial, m);
    if (lane == 0) out[node] = partial + bc2[0];
}

extern "C" void kernel_launch(void* const* d_in, const int* in_sizes, int n_in,
                              void* d_out, int out_size, void* d_ws, size_t ws_size,
                              hipStream_t stream) {
    const float* x   = (const float*)d_in[0];
    const int*   ei  = (const int*)d_in[1];
    const float* Wl0 = (const float*)d_in[2];
    const float* b0  = (const float*)d_in[3];
    const float* Wr0 = (const float*)d_in[4];
    const float* Wl1 = (const float*)d_in[5];
    const float* b1  = (const float*)d_in[6];
    const float* Wr1 = (const float*)d_in[7];
    const float* Wc1 = (const float*)d_in[8];
    const float* bc1 = (const float*)d_in[9];
    const float* Wc2 = (const float*)d_in[10];
    const float* bc2 = (const float*)d_in[11];
    float* out = (float*)d_out;

    int*   deg        = (int*)d_ws;                        // N
    int*   off        = deg + N_NODES;                     // N+1
    int*   cursor     = off + N_NODES + 1;                 // N
    int*   sorted_src = cursor + N_NODES;                  // E
    size_t used       = 3 * (size_t)N_NODES + 1 + N_EDGES;
    used              = (used + 15) & ~(size_t)15;
    float* h          = (float*)d_ws + used;               // N*64

    hipMemsetAsync(deg, 0, N_NODES * sizeof(int), stream);

    const int T = 256;
    hist_kernel<<<(N_EDGES + T - 1) / T, T, 0, stream>>>(ei, deg);
    scan_kernel<<<1, SCAN_T, 0, stream>>>(deg, off, cursor);
    scatter_kernel<<<(N_EDGES + T - 1) / T, T, 0, stream>>>(ei, cursor, sorted_src);

    const int ngrid = (N_NODES + 3) / 4;
    layer0_kernel<<<ngrid, T, 0, stream>>>(x, off, sorted_src, Wl0, Wr0, b0, h);
    layer1_kernel<<<ngrid, T, 0, stream>>>(h, off, sorted_src, Wl1, Wr1, b1,
                                           Wc1, bc1, Wc2, bc2, out);
}

// Round 4
// 373.749 us; speedup vs baseline: 5.9240x; 1.2543x over previous
//
#include <hip/hip_runtime.h>

static constexpr int N_NODES = 50000;
static constexpr int N_EDGES = 1600000;
static constexpr int CIN = 32;
static constexpr int HID = 64;
static constexpr int SBLK = 256;
static constexpr int NBLK = (N_NODES + SBLK - 1) / SBLK;   // 196

// ---------------- CSR build ----------------

__global__ void hist_kernel(const int* __restrict__ ei, int* __restrict__ deg) {
    int i = blockIdx.x * blockDim.x + threadIdx.x;
    if (i < N_EDGES) atomicAdd(&deg[ei[N_EDGES + i]], 1);
}

// block partial sums of deg
__global__ void scan1_kernel(const int* __restrict__ deg, int* __restrict__ part) {
    __shared__ int red[4];
    const int i = blockIdx.x * SBLK + threadIdx.x;
    int v = (i < N_NODES) ? deg[i] : 0;
#pragma unroll
    for (int m = 32; m > 0; m >>= 1) v += __shfl_xor(v, m);
    if ((threadIdx.x & 63) == 0) red[threadIdx.x >> 6] = v;
    __syncthreads();
    if (threadIdx.x == 0) part[blockIdx.x] = red[0] + red[1] + red[2] + red[3];
}

// single block: exclusive scan of part[NBLK]
__global__ void scan2_kernel(int* __restrict__ part) {
    __shared__ int s[SBLK];
    const int t = threadIdx.x;
    const int v = (t < NBLK) ? part[t] : 0;
    s[t] = v;
    __syncthreads();
    for (int st = 1; st < SBLK; st <<= 1) {
        int u = (t >= st) ? s[t - st] : 0;
        __syncthreads();
        s[t] += u;
        __syncthreads();
    }
    if (t < NBLK) part[t] = s[t] - v;   // exclusive base
}

// finalize: intra-block exclusive scan + base -> off, cursor
__global__ void scan3_kernel(const int* __restrict__ deg, const int* __restrict__ part,
                             int* __restrict__ off, int* __restrict__ cursor) {
    __shared__ int s[SBLK];
    const int i = blockIdx.x * SBLK + threadIdx.x;
    const int t = threadIdx.x;
    const int v = (i < N_NODES) ? deg[i] : 0;
    s[t] = v;
    __syncthreads();
    for (int st = 1; st < SBLK; st <<= 1) {
        int u = (t >= st) ? s[t - st] : 0;
        __syncthreads();
        s[t] += u;
        __syncthreads();
    }
    const int excl = s[t] - v + part[blockIdx.x];
    if (i < N_NODES) { off[i] = excl; cursor[i] = excl; }
    if (i == N_NODES - 1) off[N_NODES] = N_EDGES;
}

__global__ void scatter_kernel(const int* __restrict__ ei,
                               int* __restrict__ cursor,
                               int* __restrict__ sorted_src) {
    int i = blockIdx.x * blockDim.x + threadIdx.x;
    if (i < N_EDGES) {
        const int d = ei[N_EDGES + i];
        const int pos = atomicAdd(&cursor[d], 1);
        sorted_src[pos] = ei[i];
    }
}

// ---------------- layer 0 ----------------
// one wave per node; 8 groups x 8 lanes; group g owns edge positions ≡ g (mod 8);
// 4 independent chains -> 32 edges per main-loop iteration.
__global__ void layer0_kernel(const float* __restrict__ x,
                              const int* __restrict__ off,
                              const int* __restrict__ src,
                              const float* __restrict__ Wl,
                              const float* __restrict__ Wr,
                              const float* __restrict__ b,
                              float* __restrict__ h) {
    const int node = blockIdx.x * 4 + (threadIdx.x >> 6);
    const int lane = threadIdx.x & 63;
    if (node >= N_NODES) return;
    const int e0 = off[node], e1 = off[node + 1];
    const int deg = e1 - e0;
    const int grp = lane >> 3;       // 0..7
    const int cg  = lane & 7;        // 4 channels: 4*cg..4*cg+3

    float4 A0 = make_float4(0.f,0.f,0.f,0.f), A1 = A0, A2 = A0, A3 = A0;
    int e = e0 + grp;
    const int T = deg >> 5;
    for (int t = 0; t < T; ++t, e += 32) {
        const int s0 = src[e];
        const int s1 = src[e + 8];
        const int s2 = src[e + 16];
        const int s3 = src[e + 24];
        const float4 v0 = *reinterpret_cast<const float4*>(x + (size_t)s0 * CIN + cg * 4);
        const float4 v1 = *reinterpret_cast<const float4*>(x + (size_t)s1 * CIN + cg * 4);
        const float4 v2 = *reinterpret_cast<const float4*>(x + (size_t)s2 * CIN + cg * 4);
        const float4 v3 = *reinterpret_cast<const float4*>(x + (size_t)s3 * CIN + cg * 4);
        A0.x += v0.x; A0.y += v0.y; A0.z += v0.z; A0.w += v0.w;
        A1.x += v1.x; A1.y += v1.y; A1.z += v1.z; A1.w += v1.w;
        A2.x += v2.x; A2.y += v2.y; A2.z += v2.z; A2.w += v2.w;
        A3.x += v3.x; A3.y += v3.y; A3.z += v3.z; A3.w += v3.w;
    }
    const int r = deg & 31;          // tail positions 32T..32T+r-1
    if (grp < r) {
        const int s = src[e];
        const float4 v = *reinterpret_cast<const float4*>(x + (size_t)s * CIN + cg * 4);
        A0.x += v.x; A0.y += v.y; A0.z += v.z; A0.w += v.w;
    }
    if (grp + 8 < r) {
        const int s = src[e + 8];
        const float4 v = *reinterpret_cast<const float4*>(x + (size_t)s * CIN + cg * 4);
        A1.x += v.x; A1.y += v.y; A1.z += v.z; A1.w += v.w;
    }
    if (grp + 16 < r) {
        const int s = src[e + 16];
        const float4 v = *reinterpret_cast<const float4*>(x + (size_t)s * CIN + cg * 4);
        A2.x += v.x; A2.y += v.y; A2.z += v.z; A2.w += v.w;
    }
    if (grp + 24 < r) {
        const int s = src[e + 24];
        const float4 v = *reinterpret_cast<const float4*>(x + (size_t)s * CIN + cg * 4);
        A3.x += v.x; A3.y += v.y; A3.z += v.z; A3.w += v.w;
    }

    float m4[4] = {A0.x + A1.x + A2.x + A3.x, A0.y + A1.y + A2.y + A3.y,
                   A0.z + A1.z + A2.z + A3.z, A0.w + A1.w + A2.w + A3.w};
#pragma unroll
    for (int j = 0; j < 4; ++j) {
        m4[j] += __shfl_xor(m4[j], 8);
        m4[j] += __shfl_xor(m4[j], 16);
        m4[j] += __shfl_xor(m4[j], 32);
    }
    const float inv = 1.0f / fmaxf((float)deg, 1.0f);
#pragma unroll
    for (int j = 0; j < 4; ++j) m4[j] *= inv;

    const float4 xs = *reinterpret_cast<const float4*>(x + (size_t)node * CIN + cg * 4);
    float x4[4] = {xs.x, xs.y, xs.z, xs.w};

    float o = b[lane];
#pragma unroll
    for (int k = 0; k < CIN; ++k) {
        const float mk = __shfl(m4[k & 3], k >> 2);
        const float xk = __shfl(x4[k & 3], k >> 2);
        o = fmaf(mk, Wl[k * HID + lane], o);
        o = fmaf(xk, Wr[k * HID + lane], o);
    }
    float ss = o * o;
#pragma unroll
    for (int m = 32; m > 0; m >>= 1) ss += __shfl_xor(ss, m);
    const float v = o / fmaxf(sqrtf(ss), 1e-12f);
    h[(size_t)node * HID + lane] = fmaxf(v, 0.0f);
}

// ---------------- layer 1 + classifier ----------------
// 4 groups x 16 lanes; group g owns positions ≡ g (mod 4); 4 chains -> 16 edges/iter.
__global__ void layer1_kernel(const float* __restrict__ h,
                              const int* __restrict__ off,
                              const int* __restrict__ src,
                              const float* __restrict__ Wl,
                              const float* __restrict__ Wr,
                              const float* __restrict__ b,
                              const float* __restrict__ Wc1,
                              const float* __restrict__ bc1,
                              const float* __restrict__ Wc2,
                              const float* __restrict__ bc2,
                              float* __restrict__ out) {
    const int node = blockIdx.x * 4 + (threadIdx.x >> 6);
    const int lane = threadIdx.x & 63;
    if (node >= N_NODES) return;
    const int e0 = off[node], e1 = off[node + 1];
    const int deg = e1 - e0;
    const int grp = lane >> 4;       // 0..3
    const int cg  = lane & 15;       // 4 channels: 4*cg..4*cg+3

    float4 A0 = make_float4(0.f,0.f,0.f,0.f), A1 = A0, A2 = A0, A3 = A0;
    int e = e0 + grp;
    const int T = deg >> 4;
    for (int t = 0; t < T; ++t, e += 16) {
        const int s0 = src[e];
        const int s1 = src[e + 4];
        const int s2 = src[e + 8];
        const int s3 = src[e + 12];
        const float4 v0 = *reinterpret_cast<const float4*>(h + (size_t)s0 * HID + cg * 4);
        const float4 v1 = *reinterpret_cast<const float4*>(h + (size_t)s1 * HID + cg * 4);
        const float4 v2 = *reinterpret_cast<const float4*>(h + (size_t)s2 * HID + cg * 4);
        const float4 v3 = *reinterpret_cast<const float4*>(h + (size_t)s3 * HID + cg * 4);
        A0.x += v0.x; A0.y += v0.y; A0.z += v0.z; A0.w += v0.w;
        A1.x += v1.x; A1.y += v1.y; A1.z += v1.z; A1.w += v1.w;
        A2.x += v2.x; A2.y += v2.y; A2.z += v2.z; A2.w += v2.w;
        A3.x += v3.x; A3.y += v3.y; A3.z += v3.z; A3.w += v3.w;
    }
    const int r = deg & 15;
    if (grp < r) {
        const int s = src[e];
        const float4 v = *reinterpret_cast<const float4*>(h + (size_t)s * HID + cg * 4);
        A0.x += v.x; A0.y += v.y; A0.z += v.z; A0.w += v.w;
    }
    if (grp + 4 < r) {
        const int s = src[e + 4];
        const float4 v = *reinterpret_cast<const float4*>(h + (size_t)s * HID + cg * 4);
        A1.x += v.x; A1.y += v.y; A1.z += v.z; A1.w += v.w;
    }
    if (grp + 8 < r) {
        const int s = src[e + 8];
        const float4 v = *reinterpret_cast<const float4*>(h + (size_t)s * HID + cg * 4);
        A2.x += v.x; A2.y += v.y; A2.z += v.z; A2.w += v.w;
    }
    if (grp + 12 < r) {
        const int s = src[e + 12];
        const float4 v = *reinterpret_cast<const float4*>(h + (size_t)s * HID + cg * 4);
        A3.x += v.x; A3.y += v.y; A3.z += v.z; A3.w += v.w;
    }

    float m4[4] = {A0.x + A1.x + A2.x + A3.x, A0.y + A1.y + A2.y + A3.y,
                   A0.z + A1.z + A2.z + A3.z, A0.w + A1.w + A2.w + A3.w};
#pragma unroll
    for (int j = 0; j < 4; ++j) {
        m4[j] += __shfl_xor(m4[j], 16);
        m4[j] += __shfl_xor(m4[j], 32);
    }
    const float inv = 1.0f / fmaxf((float)deg, 1.0f);
#pragma unroll
    for (int j = 0; j < 4; ++j) m4[j] *= inv;

    const float4 hs = *reinterpret_cast<const float4*>(h + (size_t)node * HID + cg * 4);
    float h4[4] = {hs.x, hs.y, hs.z, hs.w};

    float o = b[lane];
#pragma unroll
    for (int k = 0; k < HID; ++k) {
        const float mk = __shfl(m4[k & 3], k >> 2);
        const float hk = __shfl(h4[k & 3], k >> 2);
        o = fmaf(mk, Wl[k * HID + lane], o);
        o = fmaf(hk, Wr[k * HID + lane], o);
    }
    float ss = o * o;
#pragma unroll
    for (int m = 32; m > 0; m >>= 1) ss += __shfl_xor(ss, m);
    const float v = o / fmaxf(sqrtf(ss), 1e-12f);   // normalized h2[lane]

    const int j = lane & 31;
    float cacc = bc1[j];
#pragma unroll
    for (int oo = 0; oo < HID; ++oo) {
        const float vo = __shfl(v, oo);
        cacc = fmaf(vo, Wc1[oo * 32 + j], cacc);
    }
    float partial = (lane < 32) ? fmaxf(cacc, 0.0f) * Wc2[j] : 0.0f;
#pragma unroll
    for (int m = 32; m > 0; m >>= 1) partial += __shfl_xor(partial, m);
    if (lane == 0) out[node] = partial + bc2[0];
}

extern "C" void kernel_launch(void* const* d_in, const int* in_sizes, int n_in,
                              void* d_out, int out_size, void* d_ws, size_t ws_size,
                              hipStream_t stream) {
    const float* x   = (const float*)d_in[0];
    const int*   ei  = (const int*)d_in[1];
    const float* Wl0 = (const float*)d_in[2];
    const float* b0  = (const float*)d_in[3];
    const float* Wr0 = (const float*)d_in[4];
    const float* Wl1 = (const float*)d_in[5];
    const float* b1  = (const float*)d_in[6];
    const float* Wr1 = (const float*)d_in[7];
    const float* Wc1 = (const float*)d_in[8];
    const float* bc1 = (const float*)d_in[9];
    const float* Wc2 = (const float*)d_in[10];
    const float* bc2 = (const float*)d_in[11];
    float* out = (float*)d_out;

    int*   deg        = (int*)d_ws;                        // N
    int*   off        = deg + N_NODES;                     // N+1
    int*   cursor     = off + N_NODES + 1;                 // N
    int*   part       = cursor + N_NODES;                  // NBLK
    int*   sorted_src = part + ((NBLK + 15) & ~15);        // E
    size_t used       = (sorted_src - (int*)d_ws) + N_EDGES;
    used              = (used + 15) & ~(size_t)15;
    float* h          = (float*)d_ws + used;               // N*64

    hipMemsetAsync(deg, 0, N_NODES * sizeof(int), stream);

    const int T = 256;
    hist_kernel<<<(N_EDGES + T - 1) / T, T, 0, stream>>>(ei, deg);
    scan1_kernel<<<NBLK, SBLK, 0, stream>>>(deg, part);
    scan2_kernel<<<1, SBLK, 0, stream>>>(part);
    scan3_kernel<<<NBLK, SBLK, 0, stream>>>(deg, part, off, cursor);
    scatter_kernel<<<(N_EDGES + T - 1) / T, T, 0, stream>>>(ei, cursor, sorted_src);

    const int ngrid = (N_NODES + 3) / 4;
    layer0_kernel<<<ngrid, T, 0, stream>>>(x, off, sorted_src, Wl0, Wr0, b0, h);
    layer1_kernel<<<ngrid, T, 0, stream>>>(h, off, sorted_src, Wl1, Wr1, b1,
                                           Wc1, bc1, Wc2, bc2, out);
}